// Round 15
// baseline (1414.549 us; speedup 1.0000x reference)
//
#include <hip/hip_runtime.h>
#include <hip/hip_bf16.h>
#include <stdint.h>

#define D_MODEL 1024
#define VOCAB 50257
#define VP 51200          // padded vocab
#define ROWS 4096
#define LN_EPS 1e-5f

typedef short s16x4 __attribute__((ext_vector_type(4)));
typedef short s16x8 __attribute__((ext_vector_type(8)));
typedef float f32x4 __attribute__((ext_vector_type(4)));

__device__ __forceinline__ unsigned short f2bf(float f) {
  union { __hip_bfloat16 h; unsigned short u; } cv;
  cv.h = __float2bfloat16(f);
  return cv.u;
}
__device__ __forceinline__ float bf2f(unsigned short u) {
  union { float f; unsigned int i; } c;
  c.i = ((unsigned int)u) << 16;
  return c.f;
}
__device__ __forceinline__ void gload_lds16(const void* g, void* l) {
  __builtin_amdgcn_global_load_lds(
      (const __attribute__((address_space(1))) unsigned int*)g,
      (__attribute__((address_space(3))) unsigned int*)l, 16, 0, 0);
}

// ---- enc fp32 -> bf16 [4096][1024] ----
__global__ __launch_bounds__(256) void k_cast_enc(const float* __restrict__ src,
                                                  unsigned short* __restrict__ dst) {
  const size_t i0 = ((size_t)blockIdx.x * 256 + threadIdx.x) * 8;
  const f32x4* p = reinterpret_cast<const f32x4*>(src + i0);
  f32x4 a = p[0], b = p[1];
  s16x8 o;
  o[0]=f2bf(a[0]); o[1]=f2bf(a[1]); o[2]=f2bf(a[2]); o[3]=f2bf(a[3]);
  o[4]=f2bf(b[0]); o[5]=f2bf(b[1]); o[6]=f2bf(b[2]); o[7]=f2bf(b[3]);
  *reinterpret_cast<s16x8*>(dst + i0) = o;
}

// ---- W fp32 [VOCAB][1024] -> bf16 [VP][1024] zero-padded (same layout) ----
__global__ __launch_bounds__(256) void k_pack_wlin(const float* __restrict__ src,
                                                   unsigned short* __restrict__ dst) {
  const size_t i0 = ((size_t)blockIdx.x * 256 + threadIdx.x) * 8;
  const int v = (int)(i0 >> 10);
  s16x8 o;
  if (v < VOCAB) {
    const f32x4* p = reinterpret_cast<const f32x4*>(src + i0);
    f32x4 a = p[0], b = p[1];
    o[0]=f2bf(a[0]); o[1]=f2bf(a[1]); o[2]=f2bf(a[2]); o[3]=f2bf(a[3]);
    o[4]=f2bf(b[0]); o[5]=f2bf(b[1]); o[6]=f2bf(b[2]); o[7]=f2bf(b[3]);
  } else {
    #pragma unroll
    for (int i = 0; i < 8; ++i) o[i] = 0;
  }
  *reinterpret_cast<s16x8*>(dst + i0) = o;
}

// ---- emb [VOCAB][1024] fp32 -> ET bf16 [1024][VP] (transpose, zero-pad) ----
__global__ __launch_bounds__(256) void k_pack_et(const float* __restrict__ emb,
                                                 unsigned short* __restrict__ et) {
  __shared__ float tile[32][33];
  const int v0 = blockIdx.x * 32;
  const int d0 = blockIdx.y * 32;
  const int tx = threadIdx.x, ty = threadIdx.y;  // 32 x 8
  #pragma unroll
  for (int i = 0; i < 4; ++i) {
    const int v = v0 + ty + 8 * i;
    tile[ty + 8 * i][tx] = (v < VOCAB) ? emb[(size_t)v * D_MODEL + d0 + tx] : 0.f;
  }
  __syncthreads();
  #pragma unroll
  for (int i = 0; i < 4; ++i) {
    const int d = d0 + ty + 8 * i;
    et[(size_t)d * VP + v0 + tx] = f2bf(tile[tx][ty + 8 * i]);
  }
}

// ---- GEMM1: P = exp(enc.W^T + b)  [4096 x VP] bf16-out, K=1024 ----
// 128(q) x 128(v) tile (m103/m105: the 2-barrier structure's best tile),
// 256 threads = 4 waves (2m x 2n), wave 64x64, acc[4][4], BK=64, 16 K-steps.
// q-tile FAST -> 32 consecutive blocks share one 256 KB W-tile (L2-hit).
__global__ __launch_bounds__(256)
void k_gemm1(const unsigned short* __restrict__ encb,
             const unsigned short* __restrict__ Wb,
             const float* __restrict__ bias,
             unsigned short* __restrict__ P,
             float* __restrict__ den) {
  __shared__ __align__(16) unsigned short As[128 * 64];  // 16 KB swizzled
  __shared__ __align__(16) unsigned short Bs[128 * 64];  // 16 KB swizzled

  const int bx = blockIdx.x;
  const int xcd = bx & 7, bi = bx >> 3;      // bi in [0,1600)
  const int mt_ = bi & 31;                   // q-tile FAST (W L2 reuse)
  const int nt_ = xcd * 50 + (bi >> 5);      // v-tile slow, contiguous per XCD
  const int row0 = mt_ * 128;
  const int col0 = nt_ * 128;

  const int tid = threadIdx.x;
  const int w = tid >> 6, l = tid & 63;
  const int mw = w >> 1, nw = w & 1;
  const int r16 = l & 15, g = l >> 4;

  f32x4 acc[4][4];
  #pragma unroll
  for (int a = 0; a < 4; ++a)
    #pragma unroll
    for (int b = 0; b < 4; ++b) acc[a][b] = f32x4{0.f, 0.f, 0.f, 0.f};

  uint32_t arow[4], asw[4], brow[4], bsw[4];
  #pragma unroll
  for (int t = 0; t < 4; ++t) {
    const uint32_t ar = mw * 64 + t * 16 + r16;
    arow[t] = ar * 128; asw[t] = (ar & 7) << 4;
    const uint32_t br = nw * 64 + t * 16 + r16;
    brow[t] = br * 128; bsw[t] = (br & 7) << 4;
  }

  for (int kt = 0; kt < 16; ++kt) {
    __syncthreads();   // prev compute done before overwrite
    #pragma unroll
    for (int ii = 0; ii < 4; ++ii) {  // A: 1024 16B chunks over 256 threads
      const int c = tid + ii * 256;
      const int r = c >> 3, s2 = (c & 7) ^ (r & 7);
      gload_lds16(encb + (size_t)(row0 + r) * 1024 + kt * 64 + s2 * 8, &As[c * 8]);
    }
    #pragma unroll
    for (int ii = 0; ii < 4; ++ii) {  // B: 1024 chunks
      const int c = tid + ii * 256;
      const int r = c >> 3, s2 = (c & 7) ^ (r & 7);
      gload_lds16(Wb + (size_t)(col0 + r) * 1024 + kt * 64 + s2 * 8, &Bs[c * 8]);
    }
    __syncthreads();   // vmcnt(0) drain + barrier

    #pragma unroll
    for (int kk = 0; kk < 2; ++kk) {
      const uint32_t ksl = (uint32_t)((kk * 4 + g) << 4);
      s16x8 af[4], bf[4];
      #pragma unroll
      for (int t = 0; t < 4; ++t) {
        af[t] = *reinterpret_cast<const s16x8*>(
            reinterpret_cast<const char*>(As) + arow[t] + (ksl ^ asw[t]));
        bf[t] = *reinterpret_cast<const s16x8*>(
            reinterpret_cast<const char*>(Bs) + brow[t] + (ksl ^ bsw[t]));
      }
      #pragma unroll
      for (int a = 0; a < 4; ++a)
        #pragma unroll
        for (int b = 0; b < 4; ++b)
          acc[a][b] = __builtin_amdgcn_mfma_f32_16x16x32_bf16(af[a], bf[b], acc[a][b], 0, 0, 0);
    }
  }

  // epilogue (R12-proven direct stores): exp(S+bias), P bf16, denom atomics
  float biasv[4];
  #pragma unroll
  for (int b = 0; b < 4; ++b) {
    const int v = col0 + nw * 64 + b * 16 + r16;
    biasv[b] = (v < VOCAB) ? bias[v] : 0.f;
  }
  #pragma unroll
  for (int a = 0; a < 4; ++a) {
    #pragma unroll
    for (int j = 0; j < 4; ++j) {
      const int q = row0 + mw * 64 + a * 16 + g * 4 + j;
      float rsum = 0.f;
      #pragma unroll
      for (int b = 0; b < 4; ++b) {
        const int v = col0 + nw * 64 + b * 16 + r16;
        float e = (v < VOCAB) ? __expf(acc[a][b][j] + biasv[b]) : 0.f;
        rsum += e;
        P[(size_t)q * VP + v] = f2bf(e);
      }
      rsum += __shfl_xor(rsum, 1);
      rsum += __shfl_xor(rsum, 2);
      rsum += __shfl_xor(rsum, 4);
      rsum += __shfl_xor(rsum, 8);
      if (r16 == 0) atomicAdd(&den[(size_t)q * 8 + (nt_ & 7)], rsum);
    }
  }
}

// ---- GEMM2: opart[ks] = P.ET^T slice (bf16 out), K-split 8 over VP ----
// 256(q) x 128(d) tile, BK=64, 8 waves (4m x 2n), wave 64x64, 100 K-steps.
// d-tile FAST -> 8 consecutive blocks share one 3.3 MB P-slab (fits 4 MB L2).
__global__ __launch_bounds__(512, 4)
void k_gemm2(const unsigned short* __restrict__ P,
             const unsigned short* __restrict__ ET,
             unsigned short* __restrict__ opart) {
  __shared__ __align__(16) unsigned short As[256 * 64];  // 32 KB P rows
  __shared__ __align__(16) unsigned short Bs[128 * 64];  // 16 KB ET rows

  const int bx = blockIdx.x;
  const int ks = bx & 7, bi = bx >> 3;       // XCD owns one K-split; bi in [0,128)
  const int nd = bi & 7, mt_ = bi >> 3;      // d-tile FAST (P-slab L2 reuse)
  const int row0 = mt_ * 256, col0 = nd * 128;
  const int k0 = ks * (VP / 8);              // 6400

  const int tid = threadIdx.x;
  const int w = tid >> 6, l = tid & 63;
  const int mw = w >> 1, nw = w & 1;
  const int r16 = l & 15, g = l >> 4;

  f32x4 acc[4][4];
  #pragma unroll
  for (int a = 0; a < 4; ++a)
    #pragma unroll
    for (int b = 0; b < 4; ++b) acc[a][b] = f32x4{0.f, 0.f, 0.f, 0.f};

  uint32_t arow[4], asw[4], brow[4], bsw[4];
  #pragma unroll
  for (int t = 0; t < 4; ++t) {
    const uint32_t ar = mw * 64 + t * 16 + r16;
    arow[t] = ar * 128; asw[t] = (ar & 7) << 4;
    const uint32_t br = nw * 64 + t * 16 + r16;
    brow[t] = br * 128; bsw[t] = (br & 7) << 4;
  }

  for (int kt = 0; kt < 100; ++kt) {
    const int koff = k0 + kt * 64;
    __syncthreads();
    #pragma unroll
    for (int ii = 0; ii < 4; ++ii) {  // A: 2048 chunks
      const int c = tid + ii * 512;
      const int r = c >> 3, s2 = (c & 7) ^ (r & 7);
      gload_lds16(P + (size_t)(row0 + r) * VP + koff + s2 * 8, &As[c * 8]);
    }
    #pragma unroll
    for (int ii = 0; ii < 2; ++ii) {  // B: 1024 chunks
      const int c = tid + ii * 512;
      const int r = c >> 3, s2 = (c & 7) ^ (r & 7);
      gload_lds16(ET + (size_t)(col0 + r) * VP + koff + s2 * 8, &Bs[c * 8]);
    }
    __syncthreads();

    #pragma unroll
    for (int kk = 0; kk < 2; ++kk) {
      const uint32_t ksl = (uint32_t)((kk * 4 + g) << 4);
      s16x8 af[4], bf[4];
      #pragma unroll
      for (int t = 0; t < 4; ++t) {
        af[t] = *reinterpret_cast<const s16x8*>(
            reinterpret_cast<const char*>(As) + arow[t] + (ksl ^ asw[t]));
        bf[t] = *reinterpret_cast<const s16x8*>(
            reinterpret_cast<const char*>(Bs) + brow[t] + (ksl ^ bsw[t]));
      }
      #pragma unroll
      for (int a = 0; a < 4; ++a)
        #pragma unroll
        for (int b = 0; b < 4; ++b)
          acc[a][b] = __builtin_amdgcn_mfma_f32_16x16x32_bf16(af[a], bf[b], acc[a][b], 0, 0, 0);
    }
  }

  // epilogue: bf16 partial stores (32B contiguous per 16 lanes)
  #pragma unroll
  for (int a = 0; a < 4; ++a) {
    #pragma unroll
    for (int j = 0; j < 4; ++j) {
      const int q = row0 + mw * 64 + a * 16 + g * 4 + j;
      unsigned short* orow = opart + ((size_t)ks * ROWS + q) * D_MODEL;
      #pragma unroll
      for (int b = 0; b < 4; ++b) {
        const int d = col0 + nw * 64 + b * 16 + r16;
        orow[d] = f2bf(acc[a][b][j]);
      }
    }
  }
}

// ---- LN epilogue: combine 8 bf16 partials + den, residual, LayerNorm ----
__global__ __launch_bounds__(256)
void k_ln2(const float* __restrict__ enc, const unsigned short* __restrict__ opart,
           const float* __restrict__ den, const float* __restrict__ gam,
           const float* __restrict__ bet, float* __restrict__ out) {
  __shared__ float r1[4], r2[4];
  const int row = blockIdx.x;
  const int t = threadIdx.x;
  const int d = t * 4;
  float dn = 0.f;
  #pragma unroll
  for (int s = 0; s < 8; ++s) dn += den[(size_t)row * 8 + s];
  const float inv = 1.f / dn;
  f32x4 acc = {0.f, 0.f, 0.f, 0.f};
  #pragma unroll
  for (int ks = 0; ks < 8; ++ks) {
    const s16x4 a = *reinterpret_cast<const s16x4*>(opart + ((size_t)ks * ROWS + row) * D_MODEL + d);
    #pragma unroll
    for (int jj = 0; jj < 4; ++jj) acc[jj] += bf2f((unsigned short)a[jj]);
  }
  const f32x4 e = *reinterpret_cast<const f32x4*>(enc + (size_t)row * D_MODEL + d);
  f32x4 y;
  #pragma unroll
  for (int jj = 0; jj < 4; ++jj) y[jj] = e[jj] + acc[jj] * inv;
  float s1 = y[0] + y[1] + y[2] + y[3];
  float s2 = y[0]*y[0] + y[1]*y[1] + y[2]*y[2] + y[3]*y[3];
  #pragma unroll
  for (int off = 1; off < 64; off <<= 1) {
    s1 += __shfl_xor(s1, off);
    s2 += __shfl_xor(s2, off);
  }
  if ((t & 63) == 0) { r1[t >> 6] = s1; r2[t >> 6] = s2; }
  __syncthreads();
  const float S1 = r1[0] + r1[1] + r1[2] + r1[3];
  const float S2 = r2[0] + r2[1] + r2[2] + r2[3];
  const float mean = S1 * (1.f / D_MODEL);
  const float var = S2 * (1.f / D_MODEL) - mean * mean;
  const float rs = rsqrtf(var + LN_EPS);
  const f32x4 gv = *reinterpret_cast<const f32x4*>(gam + d);
  const f32x4 bv = *reinterpret_cast<const f32x4*>(bet + d);
  f32x4 o;
  #pragma unroll
  for (int jj = 0; jj < 4; ++jj) o[jj] = (y[jj] - mean) * rs * gv[jj] + bv[jj];
  *reinterpret_cast<f32x4*>(out + (size_t)row * D_MODEL + d) = o;
}

// ============================================================================
extern "C" void kernel_launch(void* const* d_in, const int* in_sizes, int n_in,
                              void* d_out, int out_size, void* d_ws, size_t ws_size,
                              hipStream_t stream) {
  const float* enc = (const float*)d_in[0];
  const float* pw  = (const float*)d_in[1];
  const float* pb  = (const float*)d_in[2];
  const float* emb = (const float*)d_in[3];
  const float* gam = (const float*)d_in[4];
  const float* bet = (const float*)d_in[5];
  float* out = (float*)d_out;

  size_t off = 0;
  unsigned short* encb = (unsigned short*)((char*)d_ws + off); off += (size_t)ROWS * D_MODEL * 2;
  unsigned short* Wb   = (unsigned short*)((char*)d_ws + off); off += (size_t)VP * D_MODEL * 2;
  unsigned short* ET   = (unsigned short*)((char*)d_ws + off); off += (size_t)D_MODEL * VP * 2;
  unsigned short* P    = (unsigned short*)((char*)d_ws + off); off += (size_t)ROWS * VP * 2;
  unsigned short* opart = (unsigned short*)((char*)d_ws + off); off += (size_t)8 * ROWS * D_MODEL * 2;
  float* den           = (float*)((char*)d_ws + off);          off += (size_t)ROWS * 8 * 4;

  if (off > ws_size) {
    // unambiguous sentinel: ws too small -> absmax ~3.4e38
    hipMemsetAsync(d_out, 0x7f, (size_t)out_size * 4, stream);
    return;
  }

  hipMemsetAsync(den, 0, (size_t)ROWS * 8 * 4, stream);
  k_cast_enc<<<(ROWS * D_MODEL / 8) / 256, 256, 0, stream>>>(enc, encb);
  k_pack_wlin<<<((size_t)VP * D_MODEL / 8) / 256, 256, 0, stream>>>(pw, Wb);
  k_pack_et<<<dim3(VP / 32, D_MODEL / 32), dim3(32, 8), 0, stream>>>(emb, ET);
  k_gemm1<<<12800, 256, 0, stream>>>(encb, Wb, pb, P, den);
  k_gemm2<<<1024, 512, 0, stream>>>(P, ET, opart);
  k_ln2<<<ROWS, 256, 0, stream>>>(enc, opart, den, gam, bet, out);
}

// Round 16
// 1140.422 us; speedup vs baseline: 1.2404x; 1.2404x over previous
//
#include <hip/hip_runtime.h>
#include <hip/hip_bf16.h>
#include <stdint.h>

#define D_MODEL 1024
#define VOCAB 50257
#define VP 51200          // padded vocab
#define ROWS 4096
#define LN_EPS 1e-5f

typedef short s16x4 __attribute__((ext_vector_type(4)));
typedef short s16x8 __attribute__((ext_vector_type(8)));
typedef float f32x4 __attribute__((ext_vector_type(4)));

__device__ __forceinline__ unsigned short f2bf(float f) {
  union { __hip_bfloat16 h; unsigned short u; } cv;
  cv.h = __float2bfloat16(f);
  return cv.u;
}
__device__ __forceinline__ float bf2f(unsigned short u) {
  union { float f; unsigned int i; } c;
  c.i = ((unsigned int)u) << 16;
  return c.f;
}
__device__ __forceinline__ void gload_lds16(const void* g, void* l) {
  __builtin_amdgcn_global_load_lds(
      (const __attribute__((address_space(1))) unsigned int*)g,
      (__attribute__((address_space(3))) unsigned int*)l, 16, 0, 0);
}

// ---- enc fp32 -> bf16 [4096][1024] ----
__global__ __launch_bounds__(256) void k_cast_enc(const float* __restrict__ src,
                                                  unsigned short* __restrict__ dst) {
  const size_t i0 = ((size_t)blockIdx.x * 256 + threadIdx.x) * 8;
  const f32x4* p = reinterpret_cast<const f32x4*>(src + i0);
  f32x4 a = p[0], b = p[1];
  s16x8 o;
  o[0]=f2bf(a[0]); o[1]=f2bf(a[1]); o[2]=f2bf(a[2]); o[3]=f2bf(a[3]);
  o[4]=f2bf(b[0]); o[5]=f2bf(b[1]); o[6]=f2bf(b[2]); o[7]=f2bf(b[3]);
  *reinterpret_cast<s16x8*>(dst + i0) = o;
}

// ---- W fp32 [VOCAB][1024] -> bf16 [VP][1024] zero-padded (same layout) ----
__global__ __launch_bounds__(256) void k_pack_wlin(const float* __restrict__ src,
                                                   unsigned short* __restrict__ dst) {
  const size_t i0 = ((size_t)blockIdx.x * 256 + threadIdx.x) * 8;
  const int v = (int)(i0 >> 10);
  s16x8 o;
  if (v < VOCAB) {
    const f32x4* p = reinterpret_cast<const f32x4*>(src + i0);
    f32x4 a = p[0], b = p[1];
    o[0]=f2bf(a[0]); o[1]=f2bf(a[1]); o[2]=f2bf(a[2]); o[3]=f2bf(a[3]);
    o[4]=f2bf(b[0]); o[5]=f2bf(b[1]); o[6]=f2bf(b[2]); o[7]=f2bf(b[3]);
  } else {
    #pragma unroll
    for (int i = 0; i < 8; ++i) o[i] = 0;
  }
  *reinterpret_cast<s16x8*>(dst + i0) = o;
}

// ---- emb [VOCAB][1024] fp32 -> ET bf16 [1024][VP] (transpose, zero-pad) ----
__global__ __launch_bounds__(256) void k_pack_et(const float* __restrict__ emb,
                                                 unsigned short* __restrict__ et) {
  __shared__ float tile[32][33];
  const int v0 = blockIdx.x * 32;
  const int d0 = blockIdx.y * 32;
  const int tx = threadIdx.x, ty = threadIdx.y;  // 32 x 8
  #pragma unroll
  for (int i = 0; i < 4; ++i) {
    const int v = v0 + ty + 8 * i;
    tile[ty + 8 * i][tx] = (v < VOCAB) ? emb[(size_t)v * D_MODEL + d0 + tx] : 0.f;
  }
  __syncthreads();
  #pragma unroll
  for (int i = 0; i < 4; ++i) {
    const int d = d0 + ty + 8 * i;
    et[(size_t)d * VP + v0 + tx] = f2bf(tile[tx][ty + 8 * i]);
  }
}

// ---- GEMM1: P = exp(enc.W^T + b)  [4096 x VP] bf16-out, K=1024 ----
// R12-proven: 128(q) x 256(v) tile, BK=64, 8 waves (2m x 4n), wave 64x64,
// 16 K-steps. q-tile FAST -> 32 consecutive blocks share one W-tile (L2-hit).
__global__ __launch_bounds__(512, 4)
void k_gemm1(const unsigned short* __restrict__ encb,
             const unsigned short* __restrict__ Wb,
             const float* __restrict__ bias,
             unsigned short* __restrict__ P,
             float* __restrict__ den) {
  __shared__ __align__(16) unsigned short As[128 * 64];  // 16 KB swizzled
  __shared__ __align__(16) unsigned short Bs[256 * 64];  // 32 KB swizzled

  const int bx = blockIdx.x;
  const int xcd = bx & 7, bi = bx >> 3;      // bi in [0,800)
  const int mt_ = bi & 31;                   // q-tile FAST (W L2 reuse)
  const int nt_ = xcd * 25 + (bi >> 5);      // v-tile slow, contiguous per XCD
  const int row0 = mt_ * 128;
  const int col0 = nt_ * 256;

  const int tid = threadIdx.x;
  const int w = tid >> 6, l = tid & 63;
  const int mw = w >> 2, nw = w & 3;
  const int r16 = l & 15, g = l >> 4;

  f32x4 acc[4][4];
  #pragma unroll
  for (int a = 0; a < 4; ++a)
    #pragma unroll
    for (int b = 0; b < 4; ++b) acc[a][b] = f32x4{0.f, 0.f, 0.f, 0.f};

  uint32_t arow[4], asw[4], brow[4], bsw[4];
  #pragma unroll
  for (int t = 0; t < 4; ++t) {
    const uint32_t ar = mw * 64 + t * 16 + r16;
    arow[t] = ar * 128; asw[t] = (ar & 7) << 4;
    const uint32_t br = nw * 64 + t * 16 + r16;
    brow[t] = br * 128; bsw[t] = (br & 7) << 4;
  }

  for (int kt = 0; kt < 16; ++kt) {
    __syncthreads();   // prev compute done before overwrite
    #pragma unroll
    for (int ii = 0; ii < 2; ++ii) {  // A: 1024 16B chunks
      const int c = tid + ii * 512;
      const int r = c >> 3, s2 = (c & 7) ^ (r & 7);
      gload_lds16(encb + (size_t)(row0 + r) * 1024 + kt * 64 + s2 * 8, &As[c * 8]);
    }
    #pragma unroll
    for (int ii = 0; ii < 4; ++ii) {  // B: 2048 chunks
      const int c = tid + ii * 512;
      const int r = c >> 3, s2 = (c & 7) ^ (r & 7);
      gload_lds16(Wb + (size_t)(col0 + r) * 1024 + kt * 64 + s2 * 8, &Bs[c * 8]);
    }
    __syncthreads();   // vmcnt(0) drain + barrier

    #pragma unroll
    for (int kk = 0; kk < 2; ++kk) {
      const uint32_t ksl = (uint32_t)((kk * 4 + g) << 4);
      s16x8 af[4], bf[4];
      #pragma unroll
      for (int t = 0; t < 4; ++t) {
        af[t] = *reinterpret_cast<const s16x8*>(
            reinterpret_cast<const char*>(As) + arow[t] + (ksl ^ asw[t]));
        bf[t] = *reinterpret_cast<const s16x8*>(
            reinterpret_cast<const char*>(Bs) + brow[t] + (ksl ^ bsw[t]));
      }
      #pragma unroll
      for (int a = 0; a < 4; ++a)
        #pragma unroll
        for (int b = 0; b < 4; ++b)
          acc[a][b] = __builtin_amdgcn_mfma_f32_16x16x32_bf16(af[a], bf[b], acc[a][b], 0, 0, 0);
    }
  }

  // epilogue: exp(S + bias), write P bf16, per-row denom atomics
  float biasv[4];
  #pragma unroll
  for (int b = 0; b < 4; ++b) {
    const int v = col0 + nw * 64 + b * 16 + r16;
    biasv[b] = (v < VOCAB) ? bias[v] : 0.f;
  }
  #pragma unroll
  for (int a = 0; a < 4; ++a) {
    #pragma unroll
    for (int j = 0; j < 4; ++j) {
      const int q = row0 + mw * 64 + a * 16 + g * 4 + j;
      float rsum = 0.f;
      #pragma unroll
      for (int b = 0; b < 4; ++b) {
        const int v = col0 + nw * 64 + b * 16 + r16;
        float e = (v < VOCAB) ? __expf(acc[a][b][j] + biasv[b]) : 0.f;
        rsum += e;
        P[(size_t)q * VP + v] = f2bf(e);
      }
      rsum += __shfl_xor(rsum, 1);
      rsum += __shfl_xor(rsum, 2);
      rsum += __shfl_xor(rsum, 4);
      rsum += __shfl_xor(rsum, 8);
      if (r16 == 0) atomicAdd(&den[(size_t)q * 8 + (nt_ & 7)], rsum);
    }
  }
}

// ---- GEMM2: opart[ks] = P.ET^T slice (bf16 out), K-split 8 over VP ----
// 256(q) x 128(d) tile, BK=64, 8 waves (4m x 2n), wave 64x64, 100 K-steps.
// d-tile FAST -> 8 consecutive blocks share one 3.3 MB P-slab (fits 4 MB L2).
__global__ __launch_bounds__(512, 4)
void k_gemm2(const unsigned short* __restrict__ P,
             const unsigned short* __restrict__ ET,
             unsigned short* __restrict__ opart) {
  __shared__ __align__(16) unsigned short As[256 * 64];  // 32 KB P rows
  __shared__ __align__(16) unsigned short Bs[128 * 64];  // 16 KB ET rows

  const int bx = blockIdx.x;
  const int ks = bx & 7, bi = bx >> 3;       // XCD owns one K-split; bi in [0,128)
  const int nd = bi & 7, mt_ = bi >> 3;      // d-tile FAST (P-slab L2 reuse)
  const int row0 = mt_ * 256, col0 = nd * 128;
  const int k0 = ks * (VP / 8);              // 6400

  const int tid = threadIdx.x;
  const int w = tid >> 6, l = tid & 63;
  const int mw = w >> 1, nw = w & 1;
  const int r16 = l & 15, g = l >> 4;

  f32x4 acc[4][4];
  #pragma unroll
  for (int a = 0; a < 4; ++a)
    #pragma unroll
    for (int b = 0; b < 4; ++b) acc[a][b] = f32x4{0.f, 0.f, 0.f, 0.f};

  uint32_t arow[4], asw[4], brow[4], bsw[4];
  #pragma unroll
  for (int t = 0; t < 4; ++t) {
    const uint32_t ar = mw * 64 + t * 16 + r16;
    arow[t] = ar * 128; asw[t] = (ar & 7) << 4;
    const uint32_t br = nw * 64 + t * 16 + r16;
    brow[t] = br * 128; bsw[t] = (br & 7) << 4;
  }

  for (int kt = 0; kt < 100; ++kt) {
    const int koff = k0 + kt * 64;
    __syncthreads();
    #pragma unroll
    for (int ii = 0; ii < 4; ++ii) {  // A: 2048 chunks
      const int c = tid + ii * 512;
      const int r = c >> 3, s2 = (c & 7) ^ (r & 7);
      gload_lds16(P + (size_t)(row0 + r) * VP + koff + s2 * 8, &As[c * 8]);
    }
    #pragma unroll
    for (int ii = 0; ii < 2; ++ii) {  // B: 1024 chunks
      const int c = tid + ii * 512;
      const int r = c >> 3, s2 = (c & 7) ^ (r & 7);
      gload_lds16(ET + (size_t)(col0 + r) * VP + koff + s2 * 8, &Bs[c * 8]);
    }
    __syncthreads();

    #pragma unroll
    for (int kk = 0; kk < 2; ++kk) {
      const uint32_t ksl = (uint32_t)((kk * 4 + g) << 4);
      s16x8 af[4], bf[4];
      #pragma unroll
      for (int t = 0; t < 4; ++t) {
        af[t] = *reinterpret_cast<const s16x8*>(
            reinterpret_cast<const char*>(As) + arow[t] + (ksl ^ asw[t]));
        bf[t] = *reinterpret_cast<const s16x8*>(
            reinterpret_cast<const char*>(Bs) + brow[t] + (ksl ^ bsw[t]));
      }
      #pragma unroll
      for (int a = 0; a < 4; ++a)
        #pragma unroll
        for (int b = 0; b < 4; ++b)
          acc[a][b] = __builtin_amdgcn_mfma_f32_16x16x32_bf16(af[a], bf[b], acc[a][b], 0, 0, 0);
    }
  }

  // epilogue: bf16 partial stores (32B contiguous per 16 lanes)
  #pragma unroll
  for (int a = 0; a < 4; ++a) {
    #pragma unroll
    for (int j = 0; j < 4; ++j) {
      const int q = row0 + mw * 64 + a * 16 + g * 4 + j;
      unsigned short* orow = opart + ((size_t)ks * ROWS + q) * D_MODEL;
      #pragma unroll
      for (int b = 0; b < 4; ++b) {
        const int d = col0 + nw * 64 + b * 16 + r16;
        orow[d] = f2bf(acc[a][b][j]);
      }
    }
  }
}

// ---- LN epilogue: combine 8 bf16 partials + den, residual, LayerNorm ----
__global__ __launch_bounds__(256)
void k_ln2(const float* __restrict__ enc, const unsigned short* __restrict__ opart,
           const float* __restrict__ den, const float* __restrict__ gam,
           const float* __restrict__ bet, float* __restrict__ out) {
  __shared__ float r1[4], r2[4];
  const int row = blockIdx.x;
  const int t = threadIdx.x;
  const int d = t * 4;
  float dn = 0.f;
  #pragma unroll
  for (int s = 0; s < 8; ++s) dn += den[(size_t)row * 8 + s];
  const float inv = 1.f / dn;
  f32x4 acc = {0.f, 0.f, 0.f, 0.f};
  #pragma unroll
  for (int ks = 0; ks < 8; ++ks) {
    const s16x4 a = *reinterpret_cast<const s16x4*>(opart + ((size_t)ks * ROWS + row) * D_MODEL + d);
    #pragma unroll
    for (int jj = 0; jj < 4; ++jj) acc[jj] += bf2f((unsigned short)a[jj]);
  }
  const f32x4 e = *reinterpret_cast<const f32x4*>(enc + (size_t)row * D_MODEL + d);
  f32x4 y;
  #pragma unroll
  for (int jj = 0; jj < 4; ++jj) y[jj] = e[jj] + acc[jj] * inv;
  float s1 = y[0] + y[1] + y[2] + y[3];
  float s2 = y[0]*y[0] + y[1]*y[1] + y[2]*y[2] + y[3]*y[3];
  #pragma unroll
  for (int off = 1; off < 64; off <<= 1) {
    s1 += __shfl_xor(s1, off);
    s2 += __shfl_xor(s2, off);
  }
  if ((t & 63) == 0) { r1[t >> 6] = s1; r2[t >> 6] = s2; }
  __syncthreads();
  const float S1 = r1[0] + r1[1] + r1[2] + r1[3];
  const float S2 = r2[0] + r2[1] + r2[2] + r2[3];
  const float mean = S1 * (1.f / D_MODEL);
  const float var = S2 * (1.f / D_MODEL) - mean * mean;
  const float rs = rsqrtf(var + LN_EPS);
  const f32x4 gv = *reinterpret_cast<const f32x4*>(gam + d);
  const f32x4 bv = *reinterpret_cast<const f32x4*>(bet + d);
  f32x4 o;
  #pragma unroll
  for (int jj = 0; jj < 4; ++jj) o[jj] = (y[jj] - mean) * rs * gv[jj] + bv[jj];
  *reinterpret_cast<f32x4*>(out + (size_t)row * D_MODEL + d) = o;
}

// ============================================================================
extern "C" void kernel_launch(void* const* d_in, const int* in_sizes, int n_in,
                              void* d_out, int out_size, void* d_ws, size_t ws_size,
                              hipStream_t stream) {
  const float* enc = (const float*)d_in[0];
  const float* pw  = (const float*)d_in[1];
  const float* pb  = (const float*)d_in[2];
  const float* emb = (const float*)d_in[3];
  const float* gam = (const float*)d_in[4];
  const float* bet = (const float*)d_in[5];
  float* out = (float*)d_out;

  size_t off = 0;
  unsigned short* encb = (unsigned short*)((char*)d_ws + off); off += (size_t)ROWS * D_MODEL * 2;
  unsigned short* Wb   = (unsigned short*)((char*)d_ws + off); off += (size_t)VP * D_MODEL * 2;
  unsigned short* ET   = (unsigned short*)((char*)d_ws + off); off += (size_t)D_MODEL * VP * 2;
  unsigned short* P    = (unsigned short*)((char*)d_ws + off); off += (size_t)ROWS * VP * 2;
  unsigned short* opart = (unsigned short*)((char*)d_ws + off); off += (size_t)8 * ROWS * D_MODEL * 2;
  float* den           = (float*)((char*)d_ws + off);          off += (size_t)ROWS * 8 * 4;

  if (off > ws_size) {
    // unambiguous sentinel: ws too small -> absmax ~3.4e38
    hipMemsetAsync(d_out, 0x7f, (size_t)out_size * 4, stream);
    return;
  }

  hipMemsetAsync(den, 0, (size_t)ROWS * 8 * 4, stream);
  k_cast_enc<<<(ROWS * D_MODEL / 8) / 256, 256, 0, stream>>>(enc, encb);
  k_pack_wlin<<<((size_t)VP * D_MODEL / 8) / 256, 256, 0, stream>>>(pw, Wb);
  k_pack_et<<<dim3(VP / 32, D_MODEL / 32), dim3(32, 8), 0, stream>>>(emb, ET);
  k_gemm1<<<6400, 512, 0, stream>>>(encb, Wb, pb, P, den);
  k_gemm2<<<1024, 512, 0, stream>>>(P, ET, opart);
  k_ln2<<<ROWS, 256, 0, stream>>>(enc, opart, den, gam, bet, out);
}